// Round 5
// baseline (6499.026 us; speedup 1.0000x reference)
//
#include <hip/hip_runtime.h>
#include <math.h>

// Problem dims
#define BB   64
#define TT   512
#define LL   256
#define HIDD 256
#define KEYDD 128
#define VALDD 128
#define VOC  4096
#define NB   4        // blocks cooperating per batch element

__device__ __forceinline__ float sigm(float x){ return 1.0f/(1.0f+__expf(-x)); }

// Cache-bypassing system-scope relaxed accesses: data to/from the memory-side
// coherence point. No cache invalidation, no L2 writeback fences.
__device__ __forceinline__ void g_store(float* p, float v){
  __hip_atomic_store(p, v, __ATOMIC_RELAXED, __HIP_MEMORY_SCOPE_SYSTEM);
}
__device__ __forceinline__ float g_load(const float* p){
  return __hip_atomic_load(p, __ATOMIC_RELAXED, __HIP_MEMORY_SCOPE_SYSTEM);
}

// All-lane spin: same-address load coalesces to one request per wave.
__device__ __forceinline__ void spin_wait(const unsigned int* c, unsigned target){
  while (__hip_atomic_load(c, __ATOMIC_RELAXED, __HIP_MEMORY_SCOPE_SYSTEM) < target)
    __builtin_amdgcn_s_sleep(2);
  __atomic_signal_fence(__ATOMIC_SEQ_CST);   // compiler fence: no data-load hoist above spin
}

// Per-wave arrive: drain this wave's stores to the coherence point, lane0 posts.
__device__ __forceinline__ void wave_arrive(unsigned int* c){
  asm volatile("s_waitcnt vmcnt(0)" ::: "memory");
  if ((threadIdx.x & 63) == 0)
    __hip_atomic_fetch_add(c, 1u, __ATOMIC_RELAXED, __HIP_MEMORY_SCOPE_SYSTEM);
}

// Raw barrier: order LDS only (lgkmcnt), leave global loads in flight (no vmcnt drain).
__device__ __forceinline__ void bar(){
  asm volatile("s_waitcnt lgkmcnt(0)" ::: "memory");
  __builtin_amdgcn_s_barrier();
}

// ---------------------------------------------------------------------------
// One-time weight reshapes + counter zeroing.
// W1T [NB][384][256]: rows 0..255 = W_hh1 (h1prev), rows 256..383 = W_ih1 ctx cols.
//   col jj = cell*4 + gate (gate order i,f,g,o); j_global = gate*256 + r*64 + cell.
// W2T [NB][384][128]: rows 0..127 = W_hh2 (h2prev), rows 128..383 = W_ih2 (h1).
//   col jj = cell*4 + gate; j_global = gate*128 + r*32 + cell.
__global__ void prep_w(const float* __restrict__ Wi1, const float* __restrict__ Wh1,
                       const float* __restrict__ Wi2, const float* __restrict__ Wh2,
                       float* __restrict__ W1T, float* __restrict__ W2T,
                       unsigned int* __restrict__ cnt){
  int idx = blockIdx.x*blockDim.x + threadIdx.x;
  if (idx < NB*384*256){
    int r  = idx / (384*256);
    int rm = idx - r*(384*256);
    int k  = rm >> 8, jj = rm & 255;
    int cell = jj >> 2, gate = jj & 3;
    int j = gate*256 + r*64 + cell;
    W1T[idx] = (k < 256) ? Wh1[j*256 + k] : Wi1[j*384 + 256 + (k-256)];
  }
  if (idx < NB*384*128){
    int r  = idx / (384*128);
    int rm = idx - r*(384*128);
    int k  = rm >> 7, jj = rm & 127;
    int cell = jj >> 2, gate = jj & 3;
    int j = gate*128 + r*32 + cell;
    W2T[idx] = (k < 128) ? Wh2[j*128 + k] : Wi2[j*256 + (k-128)];
  }
  if (idx < BB*3*64) cnt[idx] = 0;   // padded counters: 3 per cluster, 256B apart
}

// key [B][T][K] -> keyT [B][K][T], 32x32 LDS tiles (both sides coalesced)
__global__ __launch_bounds__(256) void prep_keyT(const float* __restrict__ key,
                                                 float* __restrict__ keyT){
  __shared__ float tile[32][33];
  int bid = blockIdx.x;
  int b  = bid >> 6;
  int r  = bid & 63;
  int st = r >> 2, kt = r & 3;
  int s0 = st*32, k0 = kt*32;
  int tid = threadIdx.x;
  int kl = tid & 31, sl = tid >> 5;
  #pragma unroll
  for (int i = 0; i < 4; ++i)
    tile[sl + 8*i][kl] = key[((size_t)b*TT + s0 + sl + 8*i)*KEYDD + k0 + kl];
  __syncthreads();
  int sl2 = tid & 31, kl2 = tid >> 5;
  #pragma unroll
  for (int i = 0; i < 4; ++i)
    keyT[((size_t)b*KEYDD + k0 + kl2 + 8*i)*TT + s0 + sl2] = tile[sl2][kl2 + 8*i];
}

// ---------------------------------------------------------------------------
// P1[n][j] = sum_{k<256} emb[text[n]][k] * W_ih1[j][k] + bi1[j] + bh1[j]
__global__ __launch_bounds__(256) void pre_gemm(
    const int*   __restrict__ text, const float* __restrict__ emb,
    const float* __restrict__ Wi1,  const float* __restrict__ bi1,
    const float* __restrict__ bh1,  float* __restrict__ P1)
{
  __shared__ float As[16][132];
  __shared__ float Bs[16][132];
  const int tid = threadIdx.x;
  const int tx = tid & 15, ty = tid >> 4;
  const int bn = blockIdx.x, bm = blockIdx.y;

  float acc[8][8];
  #pragma unroll
  for (int i = 0; i < 8; ++i)
    #pragma unroll
    for (int j = 0; j < 8; ++j) acc[i][j] = 0.f;

  const int r  = tid >> 1;
  const int ko = (tid & 1) * 8;
  const int arow = text[bm*128 + r];
  const float* Ap = emb + (size_t)arow*256 + ko;
  const float* Bp = Wi1 + (size_t)(bn*128 + r)*384 + ko;

  for (int k0 = 0; k0 < 256; k0 += 16){
    float4 a0 = *(const float4*)(Ap + k0);
    float4 a1 = *(const float4*)(Ap + k0 + 4);
    float4 b0 = *(const float4*)(Bp + k0);
    float4 b1 = *(const float4*)(Bp + k0 + 4);
    As[ko+0][r]=a0.x; As[ko+1][r]=a0.y; As[ko+2][r]=a0.z; As[ko+3][r]=a0.w;
    As[ko+4][r]=a1.x; As[ko+5][r]=a1.y; As[ko+6][r]=a1.z; As[ko+7][r]=a1.w;
    Bs[ko+0][r]=b0.x; Bs[ko+1][r]=b0.y; Bs[ko+2][r]=b0.z; Bs[ko+3][r]=b0.w;
    Bs[ko+4][r]=b1.x; Bs[ko+5][r]=b1.y; Bs[ko+6][r]=b1.z; Bs[ko+7][r]=b1.w;
    __syncthreads();
    #pragma unroll
    for (int k = 0; k < 16; ++k){
      float4 x0 = *(const float4*)&As[k][ty*8];
      float4 x1 = *(const float4*)&As[k][ty*8+4];
      float4 y0 = *(const float4*)&Bs[k][tx*8];
      float4 y1 = *(const float4*)&Bs[k][tx*8+4];
      float av[8] = {x0.x,x0.y,x0.z,x0.w,x1.x,x1.y,x1.z,x1.w};
      float bv[8] = {y0.x,y0.y,y0.z,y0.w,y1.x,y1.y,y1.z,y1.w};
      #pragma unroll
      for (int i = 0; i < 8; ++i)
        #pragma unroll
        for (int j = 0; j < 8; ++j) acc[i][j] += av[i]*bv[j];
    }
    __syncthreads();
  }

  const int c0 = bn*128 + tx*8;
  float bl[8];
  #pragma unroll
  for (int j = 0; j < 8; ++j) bl[j] = bi1[c0 + j] + bh1[c0 + j];
  #pragma unroll
  for (int i = 0; i < 8; ++i){
    size_t row = (size_t)(bm*128 + ty*8 + i);
    float4 o0 = make_float4(acc[i][0]+bl[0], acc[i][1]+bl[1], acc[i][2]+bl[2], acc[i][3]+bl[3]);
    float4 o1 = make_float4(acc[i][4]+bl[4], acc[i][5]+bl[5], acc[i][6]+bl[6], acc[i][7]+bl[7]);
    *(float4*)(P1 + row*1024 + c0)     = o0;
    *(float4*)(P1 + row*1024 + c0 + 4) = o1;
  }
}

// ---------------------------------------------------------------------------
// Recurrence: NB=4 blocks per batch element, 1024 threads each (grid = 256 CUs).
// key slice staged in LDS once; values slice held in registers (step-invariant).
// Raw lgkm-only barriers; all-lane spins; per-wave vmcnt+atomic arrives.
__global__ __launch_bounds__(1024) void rec_kernel(
    const float* __restrict__ keyT, const float* __restrict__ values,
    const float* __restrict__ P1,   const float* __restrict__ W1T,
    const float* __restrict__ W2T,  const float* __restrict__ bi2,
    const float* __restrict__ bh2,  float* __restrict__ states,
    float* __restrict__ h1buf, float* __restrict__ h2buf,
    float* __restrict__ axc,  unsigned int* __restrict__ cnt)
{
  const int bid = blockIdx.x;
  const int b = bid >> 2, r = bid & 3;
  const int tid = threadIdx.x;

  __shared__ __align__(16) float key_lds[128*128]; // [k][s-slice] 64 KB
  __shared__ __align__(16) float part[4096];       // split-K partials (16 KB)
  __shared__ __align__(16) float ST[512];          // [ctx 0:128 | h1 128:384 | h2 384:512]
  __shared__ __align__(16) float b2loc[128];       // cell*4+gate
  __shared__ float att[128];

  if (tid < 512) ST[tid] = 0.f;
  if (tid < 128){
    int c = tid >> 2, g = tid & 3;
    b2loc[tid] = bi2[g*128 + r*32 + c] + bh2[g*128 + r*32 + c];
  }
  // stage key slice: keyT[b][k][r*128 .. r*128+128)
  {
    const float4* kg = reinterpret_cast<const float4*>(keyT + (size_t)b*KEYDD*TT);
    float4* kl = reinterpret_cast<float4*>(key_lds);
    #pragma unroll
    for (int i = 0; i < 4; ++i){
      int q = tid + i*1024;            // 0..4095
      int k = q >> 5, c = q & 31;
      kl[k*32 + c] = kg[(size_t)k*128 + r*32 + c];
    }
  }
  // values slice to registers: thread (vg = tid&31, sc = tid>>5) holds s = sc*4+i
  const int vg = tid & 31, sc = tid >> 5;
  const float4* valB4 = reinterpret_cast<const float4*>(values + (size_t)b*TT*VALDD);
  float4 vv0 = valB4[(size_t)(r*128 + sc*4 + 0)*32 + vg];
  float4 vv1 = valB4[(size_t)(r*128 + sc*4 + 1)*32 + vg];
  float4 vv2 = valB4[(size_t)(r*128 + sc*4 + 2)*32 + vg];
  float4 vv3 = valB4[(size_t)(r*128 + sc*4 + 3)*32 + vg];

  float c1 = 0.f, c2 = 0.f;            // cell slices in regs (tid<64 / tid<32)
  __syncthreads();

  const float4* W1r4 = reinterpret_cast<const float4*>(W1T) + (size_t)r*384*64;
  const float4* W2r4 = reinterpret_cast<const float4*>(W2T) + (size_t)r*384*32;
  const float*  P1b  = P1 + (size_t)b*LL*1024;
  unsigned int* cA = cnt + (b*3 + 0)*64;
  unsigned int* cB = cnt + (b*3 + 1)*64;
  unsigned int* cC = cnt + (b*3 + 2)*64;
  float* axb = axc + (size_t)b*NB*132;
  float* h1g = h1buf + b*256;
  float* h2g = h2buf + b*128;

  const int ogA = tid & 63, kcA = tid >> 6;   // LSTM1: 64 cells(x4 gates) x 16 k-chunks
  const int ogB = tid & 31, kcB = tid >> 5;   // LSTM2: 32 cells(x4 gates) x 32 k-chunks
  float4* part4 = reinterpret_cast<float4*>(part);

  // ---- prologue: h1[0] from P1 only (h1prev=0, ctx=0)
  if (tid < 64){
    float s0 = P1b[      r*64 + tid];
    float s1 = P1b[256 + r*64 + tid]; (void)s1;
    float s2 = P1b[512 + r*64 + tid];
    float s3 = P1b[768 + r*64 + tid];
    float c = sigm(s0)*tanhf(s2);            // f-gate * 0 dropped
    c1 = c;
    g_store(h1g + r*64 + tid, sigm(s3)*tanhf(c));
    wave_arrive(cA);
  }
  spin_wait(cA, NB);
  {
    float h1v = (tid < 256) ? g_load(h1g + tid) : 0.f;
    if (tid < 256) ST[128+tid] = h1v;
  }
  bar();
  // B2(0): h1 rows only (h2prev = 0)
  {
    float4 accB = make_float4(0.f,0.f,0.f,0.f);
    const float4* wp = W2r4 + (size_t)(128 + kcB*8)*32 + ogB;
    #pragma unroll
    for (int i = 0; i < 8; ++i){
      float4 w = wp[(size_t)i*32];
      float  x = ST[128 + kcB*8 + i];
      accB.x += x*w.x; accB.y += x*w.y; accB.z += x*w.z; accB.w += x*w.w;
    }
    part4[kcB*32 + ogB] = accB;
  }
  bar();
  if (tid < 32){
    float4 s = reinterpret_cast<const float4*>(b2loc)[tid];
    #pragma unroll
    for (int kc = 0; kc < 32; ++kc){
      float4 p = part4[kc*32 + tid];
      s.x += p.x; s.y += p.y; s.z += p.z; s.w += p.w;
    }
    float c = sigm(s.y)*c2 + sigm(s.x)*tanhf(s.z); c2 = c;
    float h2 = sigm(s.w)*tanhf(c);
    g_store(h2g + r*32 + tid, h2);
    states[((size_t)b*LL + 0)*256 + r*32 + tid] = h2;
  }
  if (tid < 64) wave_arrive(cB);

  // ---- main loop: iter t computes C(t) and (if t<LL-1) h1[t+1], h2[t+1]
  for (int t = 0; t < LL; ++t){
    const bool last = (t == LL-1);
    float p10=0.f, p11=0.f, p12=0.f, p13=0.f;
    if (!last && tid < 64){
      const float* pp = P1b + (size_t)(t+1)*1024;
      p10 = pp[      r*64 + tid];
      p11 = pp[256 + r*64 + tid];
      p12 = pp[512 + r*64 + tid];
      p13 = pp[768 + r*64 + tid];
    }
    float4 accA = make_float4(0.f,0.f,0.f,0.f);
    if (!last){                                  // A1a: h1 rows, i 0..3 (covers cB skew)
      const float4* wp = W1r4 + (size_t)(kcA*16)*64 + ogA;
      #pragma unroll
      for (int i = 0; i < 4; ++i){
        float4 w = wp[(size_t)i*64];
        float  x = ST[128 + kcA*16 + i];
        accA.x += x*w.x; accA.y += x*w.y; accA.z += x*w.z; accA.w += x*w.w;
      }
    }
    // wait h2[t]; issue fill; overlap with A1b; commit
    spin_wait(cB, (unsigned)((t+1)*NB));
    float hv = (tid < 128) ? g_load(h2g + tid) : 0.f;
    if (!last){                                  // A1b: i 4..11 (covers fill latency)
      const float4* wp = W1r4 + (size_t)(kcA*16 + 4)*64 + ogA;
      #pragma unroll
      for (int i = 0; i < 8; ++i){
        float4 w = wp[(size_t)i*64];
        float  x = ST[128 + kcA*16 + 4 + i];
        accA.x += x*w.x; accA.y += x*w.y; accA.z += x*w.z; accA.w += x*w.w;
      }
    }
    if (tid < 128) ST[384+tid] = hv;
    bar();                                                          // (1)

    // ---- C(t): energies from LDS key x h2
    {
      const int sg = tid & 31, kc = tid >> 5;    // 32 s-groups(x4) x 32 k-chunks(4)
      const float4* kp = reinterpret_cast<const float4*>(key_lds) + (size_t)(kc*4)*32 + sg;
      float4 acc = make_float4(0.f,0.f,0.f,0.f);
      #pragma unroll
      for (int i = 0; i < 4; ++i){
        float4 kv = kp[(size_t)i*32];
        float  h  = ST[384 + kc*4 + i];
        acc.x += h*kv.x; acc.y += h*kv.y; acc.z += h*kv.z; acc.w += h*kv.w;
      }
      part4[kc*32 + sg] = acc;
    }
    bar();                                                          // (2)
    // softmax by wave0 (lane handles s=lane, s=64+lane)
    float Mreg = 0.f, Sreg = 0.f;
    if (tid < 64){
      float ea = 0.f, eb = 0.f;
      #pragma unroll
      for (int kc = 0; kc < 32; ++kc){
        ea += part[kc*128 + tid];
        eb += part[kc*128 + 64 + tid];
      }
      float m = fmaxf(ea, eb);
      #pragma unroll
      for (int off = 32; off > 0; off >>= 1) m = fmaxf(m, __shfl_xor(m, off));
      float pa = __expf(ea - m), pb = __expf(eb - m);
      float ss = pa + pb;
      #pragma unroll
      for (int off = 32; off > 0; off >>= 1) ss += __shfl_xor(ss, off);
      att[tid] = pa; att[64+tid] = pb;
      Mreg = m; Sreg = ss;
    }
    bar();                                                          // (3)
    // ctx partial from register-resident values
    {
      float a0 = att[sc*4+0], a1 = att[sc*4+1], a2 = att[sc*4+2], a3 = att[sc*4+3];
      float4 acc;
      acc.x = a0*vv0.x + a1*vv1.x + a2*vv2.x + a3*vv3.x;
      acc.y = a0*vv0.y + a1*vv1.y + a2*vv2.y + a3*vv3.y;
      acc.z = a0*vv0.z + a1*vv1.z + a2*vv2.z + a3*vv3.z;
      acc.w = a0*vv0.w + a1*vv1.w + a2*vv2.w + a3*vv3.w;
      part4[sc*32 + vg] = acc;
    }
    bar();                                                          // (4)
    if (tid < 128){
      float cx = 0.f;
      #pragma unroll
      for (int kc = 0; kc < 32; ++kc) cx += part[kc*128 + tid];
      g_store(axb + r*132 + tid, cx);
      if (tid == 0){ g_store(axb + r*132 + 128, Mreg); g_store(axb + r*132 + 129, Sreg); }
    }
    if (tid < 128) wave_arrive(cC);              // waves 0,1 each post (+2/block)

    if (!last){                                  // A1c: i 12..15 (covers cC skew)
      const float4* wp = W1r4 + (size_t)(kcA*16 + 12)*64 + ogA;
      #pragma unroll
      for (int i = 0; i < 4; ++i){
        float4 w = wp[(size_t)i*64];
        float  x = ST[128 + kcA*16 + 12 + i];
        accA.x += x*w.x; accA.y += x*w.y; accA.z += x*w.z; accA.w += x*w.w;
      }
    }
    // wait ctx partials; flash combine
    spin_wait(cC, (unsigned)(2u*(t+1)*NB));
    if (tid < 128){
      float m0 = g_load(axb+128),     m1 = g_load(axb+132+128);
      float m2 = g_load(axb+264+128), m3 = g_load(axb+396+128);
      float s0 = g_load(axb+129),     s1 = g_load(axb+132+129);
      float s2 = g_load(axb+264+129), s3 = g_load(axb+396+129);
      float x0 = g_load(axb+tid),     x1 = g_load(axb+132+tid);
      float x2 = g_load(axb+264+tid), x3 = g_load(axb+396+tid);
      float M  = fmaxf(fmaxf(m0,m1), fmaxf(m2,m3));
      float w0 = __expf(m0-M), w1 = __expf(m1-M), w2 = __expf(m2-M), w3 = __expf(m3-M);
      float inv = 1.0f/(w0*s0 + w1*s1 + w2*s2 + w3*s3);
      float cx  = (w0*x0 + w1*x1 + w2*x2 + w3*x3)*inv;
      ST[tid] = cx;
      if ((tid >> 5) == r)
        states[((size_t)b*LL + t)*256 + 128 + tid] = cx;
    }
    bar();                                                          // (5)
    if (last) break;

    // ---- A2: ctx rows; complete LSTM1 gates for t+1
    {
      const float4* wp = W1r4 + (size_t)(256 + kcA*8)*64 + ogA;
      #pragma unroll
      for (int i = 0; i < 8; ++i){
        float4 w = wp[(size_t)i*64];
        float  x = ST[kcA*8 + i];
        accA.x += x*w.x; accA.y += x*w.y; accA.z += x*w.z; accA.w += x*w.w;
      }
      part4[kcA*64 + ogA] = accA;
    }
    bar();                                                          // (6)
    if (tid < 64){
      float4 s = make_float4(p10, p11, p12, p13);
      #pragma unroll
      for (int kc = 0; kc < 16; ++kc){
        float4 p = part4[kc*64 + tid];
        s.x += p.x; s.y += p.y; s.z += p.z; s.w += p.w;
      }
      float c = sigm(s.y)*c1 + sigm(s.x)*tanhf(s.z); c1 = c;
      g_store(h1g + r*64 + tid, sigm(s.w)*tanhf(c));
      wave_arrive(cA);
    }
    // ---- B1: h2prev rows (covers cA flight) — uses ST[384:512] = h2[t]
    float4 accB = make_float4(0.f,0.f,0.f,0.f);
    {
      const float4* wp = W2r4 + (size_t)(kcB*4)*32 + ogB;
      #pragma unroll
      for (int i = 0; i < 4; ++i){
        float4 w = wp[(size_t)i*32];
        float  x = ST[384 + kcB*4 + i];
        accB.x += x*w.x; accB.y += x*w.y; accB.z += x*w.z; accB.w += x*w.w;
      }
    }
    spin_wait(cA, (unsigned)((t+2)*NB));
    {
      float h1v = (tid < 256) ? g_load(h1g + tid) : 0.f;
      if (tid < 256) ST[128+tid] = h1v;
    }
    bar();                                                          // (7)
    // ---- B2: h1 rows
    {
      const float4* wp = W2r4 + (size_t)(128 + kcB*8)*32 + ogB;
      #pragma unroll
      for (int i = 0; i < 8; ++i){
        float4 w = wp[(size_t)i*32];
        float  x = ST[128 + kcB*8 + i];
        accB.x += x*w.x; accB.y += x*w.y; accB.z += x*w.z; accB.w += x*w.w;
      }
      part4[kcB*32 + ogB] = accB;
    }
    bar();                                                          // (8)
    if (tid < 32){
      float4 s = reinterpret_cast<const float4*>(b2loc)[tid];
      #pragma unroll
      for (int kc = 0; kc < 32; ++kc){
        float4 p = part4[kc*32 + tid];
        s.x += p.x; s.y += p.y; s.z += p.z; s.w += p.w;
      }
      float c = sigm(s.y)*c2 + sigm(s.x)*tanhf(s.z); c2 = c;
      float h2 = sigm(s.w)*tanhf(c);
      g_store(h2g + r*32 + tid, h2);
      states[((size_t)b*LL + t + 1)*256 + r*32 + tid] = h2;
    }
    if (tid < 64) wave_arrive(cB);
  }
}

// ---------------------------------------------------------------------------
// Final logits GEMM: C[n][v] = states[n][:] . emb[v][:] + b_out[v]
__global__ __launch_bounds__(256) void gemm_kernel(
    const float* __restrict__ A, const float* __restrict__ Bm,
    const float* __restrict__ bias, float* __restrict__ C)
{
  __shared__ float As[16][132];
  __shared__ float Bs[16][132];
  const int tid = threadIdx.x;
  const int tx = tid & 15, ty = tid >> 4;
  const int bn = blockIdx.x, bm = blockIdx.y;

  float acc[8][8];
  #pragma unroll
  for (int i = 0; i < 8; ++i)
    #pragma unroll
    for (int j = 0; j < 8; ++j) acc[i][j] = 0.f;

  const int r  = tid >> 1;
  const int ko = (tid & 1) * 8;
  const float* Ap = A  + ((size_t)(bm*128 + r))*256 + ko;
  const float* Bp = Bm + ((size_t)(bn*128 + r))*256 + ko;

  for (int k0 = 0; k0 < 256; k0 += 16){
    float4 a0 = *(const float4*)(Ap + k0);
    float4 a1 = *(const float4*)(Ap + k0 + 4);
    float4 b0 = *(const float4*)(Bp + k0);
    float4 b1 = *(const float4*)(Bp + k0 + 4);
    As[ko+0][r]=a0.x; As[ko+1][r]=a0.y; As[ko+2][r]=a0.z; As[ko+3][r]=a0.w;
    As[ko+4][r]=a1.x; As[ko+5][r]=a1.y; As[ko+6][r]=a1.z; As[ko+7][r]=a1.w;
    Bs[ko+0][r]=b0.x; Bs[ko+1][r]=b0.y; Bs[ko+2][r]=b0.z; Bs[ko+3][r]=b0.w;
    Bs[ko+4][r]=b1.x; Bs[ko+5][r]=b1.y; Bs[ko+6][r]=b1.z; Bs[ko+7][r]=b1.w;
    __syncthreads();
    #pragma unroll
    for (int k = 0; k < 16; ++k){
      float4 x0 = *(const float4*)&As[k][ty*8];
      float4 x1 = *(const float4*)&As[k][ty*8+4];
      float4 y0 = *(const float4*)&Bs[k][tx*8];
      float4 y1 = *(const float4*)&Bs[k][tx*8+4];
      float av[8] = {x0.x,x0.y,x0.z,x0.w,x1.x,x1.y,x1.z,x1.w};
      float bv[8] = {y0.x,y0.y,y0.z,y0.w,y1.x,y1.y,y1.z,y1.w};
      #pragma unroll
      for (int i = 0; i < 8; ++i)
        #pragma unroll
        for (int j = 0; j < 8; ++j) acc[i][j] += av[i]*bv[j];
    }
    __syncthreads();
  }

  const int c0 = bn*128 + tx*8;
  float bl[8];
  #pragma unroll
  for (int j = 0; j < 8; ++j) bl[j] = bias[c0 + j];
  #pragma unroll
  for (int i = 0; i < 8; ++i){
    size_t row = (size_t)(bm*128 + ty*8 + i);
    float4 o0 = make_float4(acc[i][0]+bl[0], acc[i][1]+bl[1], acc[i][2]+bl[2], acc[i][3]+bl[3]);
    float4 o1 = make_float4(acc[i][4]+bl[4], acc[i][5]+bl[5], acc[i][6]+bl[6], acc[i][7]+bl[7]);
    *(float4*)(C + row*4096 + c0)     = o0;
    *(float4*)(C + row*4096 + c0 + 4) = o1;
  }
}

extern "C" void kernel_launch(void* const* d_in, const int* in_sizes, int n_in,
                              void* d_out, int out_size, void* d_ws, size_t ws_size,
                              hipStream_t stream)
{
  const float* key    = (const float*)d_in[0];
  const float* values = (const float*)d_in[1];
  // d_in[2] = lens (unused by reference path)
  const int*   text   = (const int*)  d_in[3];
  const float* emb    = (const float*)d_in[4];
  const float* Wi1    = (const float*)d_in[5];
  const float* Wh1    = (const float*)d_in[6];
  const float* bi1    = (const float*)d_in[7];
  const float* bh1    = (const float*)d_in[8];
  const float* Wi2    = (const float*)d_in[9];
  const float* Wh2    = (const float*)d_in[10];
  const float* bi2    = (const float*)d_in[11];
  const float* bh2    = (const float*)d_in[12];
  const float* bout   = (const float*)d_in[13];

  // workspace (floats): states[16384*256] | W1T[4*384*256] | W2T[4*384*128] (~19.1 MB)
  float* states = (float*)d_ws;
  float* W1T    = states + (size_t)BB*LL*256;
  float* W2T    = W1T + (size_t)NB*384*256;

  // scratch inside d_out (268 MB; dead until final GEMM overwrites it):
  // P1[16384*1024] | keyT[64*128*512] | h1buf[64*256] | h2buf[64*128]
  // | axc[64*4*132] | cnt[64*3*64 uint]
  float* P1    = (float*)d_out;
  float* keyT  = P1 + (size_t)16384*1024;
  float* h1buf = keyT + (size_t)BB*KEYDD*TT;
  float* h2buf = h1buf + (size_t)BB*256;
  float* axc   = h2buf + (size_t)BB*128;
  unsigned int* cnt = (unsigned int*)(axc + (size_t)BB*NB*132);

  prep_w   <<<1536, 256, 0, stream>>>(Wi1, Wh1, Wi2, Wh2, W1T, W2T, cnt);
  prep_keyT<<<4096, 256, 0, stream>>>(key, keyT);
  pre_gemm <<<dim3(1024/128, 16384/128), 256, 0, stream>>>(text, emb, Wi1, bi1, bh1, P1);
  rec_kernel<<<BB*NB, 1024, 0, stream>>>(keyT, values, P1, W1T, W2T, bi2, bh2, states,
                                         h1buf, h2buf, axc, cnt);
  dim3 grid(VOC/128, (BB*LL)/128);
  gemm_kernel<<<grid, 256, 0, stream>>>(states, emb, bout, (float*)d_out);
}

// Round 6
// 3600.824 us; speedup vs baseline: 1.8049x; 1.8049x over previous
//
#include <hip/hip_runtime.h>
#include <math.h>

// Problem dims
#define BB   64
#define TT   512
#define LL   256
#define HIDD 256
#define KEYDD 128
#define VALDD 128
#define VOC  4096
#define NB   4        // blocks cooperating per batch element

__device__ __forceinline__ float sigm(float x){ return 1.0f/(1.0f+__expf(-x)); }
// NaN-safe fast tanh: 1 - 2/(e^{2x}+1)  (exp overflow -> 1, underflow -> -1)
__device__ __forceinline__ float ftanh(float x){ return 1.0f - 2.0f/(__expf(2.0f*x)+1.0f); }

// Cache-bypassing system-scope relaxed accesses: data to/from the memory-side
// coherence point. No cache invalidation, no L2 writeback fences.
__device__ __forceinline__ void g_store(float* p, float v){
  __hip_atomic_store(p, v, __ATOMIC_RELAXED, __HIP_MEMORY_SCOPE_SYSTEM);
}
__device__ __forceinline__ float g_load(const float* p){
  return __hip_atomic_load(p, __ATOMIC_RELAXED, __HIP_MEMORY_SCOPE_SYSTEM);
}

// Global spin (wave0 only; same-address lanes coalesce to one request).
__device__ __forceinline__ void spin_wait(const unsigned int* c, unsigned target){
  while (__hip_atomic_load(c, __ATOMIC_RELAXED, __HIP_MEMORY_SCOPE_SYSTEM) < target)
    __builtin_amdgcn_s_sleep(1);
  __atomic_signal_fence(__ATOMIC_SEQ_CST);
}

// LDS-flag wait for the other waves: on-CU polling, no fabric traffic.
__device__ __forceinline__ void lds_waitf(volatile unsigned* f, unsigned v){
  while (*f < v) __builtin_amdgcn_s_sleep(1);
  __atomic_signal_fence(__ATOMIC_SEQ_CST);
}

// Per-wave arrive: drain this wave's stores to the coherence point, lane0 posts.
__device__ __forceinline__ void wave_arrive(unsigned int* c){
  asm volatile("s_waitcnt vmcnt(0)" ::: "memory");
  if ((threadIdx.x & 63) == 0)
    __hip_atomic_fetch_add(c, 1u, __ATOMIC_RELAXED, __HIP_MEMORY_SCOPE_SYSTEM);
}

// Raw barrier: order LDS only (lgkmcnt), leave global loads in flight.
__device__ __forceinline__ void bar(){
  asm volatile("s_waitcnt lgkmcnt(0)" ::: "memory");
  __builtin_amdgcn_s_barrier();
}

// ---------------------------------------------------------------------------
// One-time weight reshapes + counter zeroing.
// W1T [NB][384][256]: rows 0..255 = W_hh1 (h1prev), rows 256..383 = W_ih1 ctx cols.
//   col jj = cell*4 + gate (gate order i,f,g,o); j_global = gate*256 + r*64 + cell.
// W2T [NB][384][128]: rows 0..127 = W_hh2 (h2prev), rows 128..383 = W_ih2 (h1).
//   col jj = cell*4 + gate; j_global = gate*128 + r*32 + cell.
__global__ void prep_w(const float* __restrict__ Wi1, const float* __restrict__ Wh1,
                       const float* __restrict__ Wi2, const float* __restrict__ Wh2,
                       float* __restrict__ W1T, float* __restrict__ W2T,
                       unsigned int* __restrict__ cnt){
  int idx = blockIdx.x*blockDim.x + threadIdx.x;
  if (idx < NB*384*256){
    int r  = idx / (384*256);
    int rm = idx - r*(384*256);
    int k  = rm >> 8, jj = rm & 255;
    int cell = jj >> 2, gate = jj & 3;
    int j = gate*256 + r*64 + cell;
    W1T[idx] = (k < 256) ? Wh1[j*256 + k] : Wi1[j*384 + 256 + (k-256)];
  }
  if (idx < NB*384*128){
    int r  = idx / (384*128);
    int rm = idx - r*(384*128);
    int k  = rm >> 7, jj = rm & 127;
    int cell = jj >> 2, gate = jj & 3;
    int j = gate*128 + r*32 + cell;
    W2T[idx] = (k < 128) ? Wh2[j*128 + k] : Wi2[j*256 + (k-128)];
  }
  if (idx < BB*3*64) cnt[idx] = 0;   // padded counters: 3 per cluster, 256B apart
}

// key [B][T][K] -> keyT [B][K][T], 32x32 LDS tiles (both sides coalesced)
__global__ __launch_bounds__(256) void prep_keyT(const float* __restrict__ key,
                                                 float* __restrict__ keyT){
  __shared__ float tile[32][33];
  int bid = blockIdx.x;
  int b  = bid >> 6;
  int r  = bid & 63;
  int st = r >> 2, kt = r & 3;
  int s0 = st*32, k0 = kt*32;
  int tid = threadIdx.x;
  int kl = tid & 31, sl = tid >> 5;
  #pragma unroll
  for (int i = 0; i < 4; ++i)
    tile[sl + 8*i][kl] = key[((size_t)b*TT + s0 + sl + 8*i)*KEYDD + k0 + kl];
  __syncthreads();
  int sl2 = tid & 31, kl2 = tid >> 5;
  #pragma unroll
  for (int i = 0; i < 4; ++i)
    keyT[((size_t)b*KEYDD + k0 + kl2 + 8*i)*TT + s0 + sl2] = tile[sl2][kl2 + 8*i];
}

// ---------------------------------------------------------------------------
// P1[n][j] = sum_{k<256} emb[text[n]][k] * W_ih1[j][k] + bi1[j] + bh1[j]
__global__ __launch_bounds__(256) void pre_gemm(
    const int*   __restrict__ text, const float* __restrict__ emb,
    const float* __restrict__ Wi1,  const float* __restrict__ bi1,
    const float* __restrict__ bh1,  float* __restrict__ P1)
{
  __shared__ float As[16][132];
  __shared__ float Bs[16][132];
  const int tid = threadIdx.x;
  const int tx = tid & 15, ty = tid >> 4;
  const int bn = blockIdx.x, bm = blockIdx.y;

  float acc[8][8];
  #pragma unroll
  for (int i = 0; i < 8; ++i)
    #pragma unroll
    for (int j = 0; j < 8; ++j) acc[i][j] = 0.f;

  const int r  = tid >> 1;
  const int ko = (tid & 1) * 8;
  const int arow = text[bm*128 + r];
  const float* Ap = emb + (size_t)arow*256 + ko;
  const float* Bp = Wi1 + (size_t)(bn*128 + r)*384 + ko;

  for (int k0 = 0; k0 < 256; k0 += 16){
    float4 a0 = *(const float4*)(Ap + k0);
    float4 a1 = *(const float4*)(Ap + k0 + 4);
    float4 b0 = *(const float4*)(Bp + k0);
    float4 b1 = *(const float4*)(Bp + k0 + 4);
    As[ko+0][r]=a0.x; As[ko+1][r]=a0.y; As[ko+2][r]=a0.z; As[ko+3][r]=a0.w;
    As[ko+4][r]=a1.x; As[ko+5][r]=a1.y; As[ko+6][r]=a1.z; As[ko+7][r]=a1.w;
    Bs[ko+0][r]=b0.x; Bs[ko+1][r]=b0.y; Bs[ko+2][r]=b0.z; Bs[ko+3][r]=b0.w;
    Bs[ko+4][r]=b1.x; Bs[ko+5][r]=b1.y; Bs[ko+6][r]=b1.z; Bs[ko+7][r]=b1.w;
    __syncthreads();
    #pragma unroll
    for (int k = 0; k < 16; ++k){
      float4 x0 = *(const float4*)&As[k][ty*8];
      float4 x1 = *(const float4*)&As[k][ty*8+4];
      float4 y0 = *(const float4*)&Bs[k][tx*8];
      float4 y1 = *(const float4*)&Bs[k][tx*8+4];
      float av[8] = {x0.x,x0.y,x0.z,x0.w,x1.x,x1.y,x1.z,x1.w};
      float bv[8] = {y0.x,y0.y,y0.z,y0.w,y1.x,y1.y,y1.z,y1.w};
      #pragma unroll
      for (int i = 0; i < 8; ++i)
        #pragma unroll
        for (int j = 0; j < 8; ++j) acc[i][j] += av[i]*bv[j];
    }
    __syncthreads();
  }

  const int c0 = bn*128 + tx*8;
  float bl[8];
  #pragma unroll
  for (int j = 0; j < 8; ++j) bl[j] = bi1[c0 + j] + bh1[c0 + j];
  #pragma unroll
  for (int i = 0; i < 8; ++i){
    size_t row = (size_t)(bm*128 + ty*8 + i);
    float4 o0 = make_float4(acc[i][0]+bl[0], acc[i][1]+bl[1], acc[i][2]+bl[2], acc[i][3]+bl[3]);
    float4 o1 = make_float4(acc[i][4]+bl[4], acc[i][5]+bl[5], acc[i][6]+bl[6], acc[i][7]+bl[7]);
    *(float4*)(P1 + row*1024 + c0)     = o0;
    *(float4*)(P1 + row*1024 + c0 + 4) = o1;
  }
}

// ---------------------------------------------------------------------------
// Recurrence: NB=4 blocks per batch element, 1024 threads each (grid = 256 CUs).
// key slice in LDS; values slice in registers. Hierarchical waits: wave0 spins
// on the global counter, publishes epoch to an LDS flag; other waves poll LDS.
__global__ __launch_bounds__(1024) void rec_kernel(
    const float* __restrict__ keyT, const float* __restrict__ values,
    const float* __restrict__ P1,   const float* __restrict__ W1T,
    const float* __restrict__ W2T,  const float* __restrict__ bi2,
    const float* __restrict__ bh2,  float* __restrict__ states,
    float* __restrict__ h1buf, float* __restrict__ h2buf,
    float* __restrict__ axc,  unsigned int* __restrict__ cnt)
{
  const int bid = blockIdx.x;
  const int b = bid >> 2, r = bid & 3;
  const int tid = threadIdx.x;

  __shared__ __align__(16) float key_lds[128*128]; // [k][s-slice] 64 KB
  __shared__ __align__(16) float part[4096];       // split-K partials (16 KB)
  __shared__ __align__(16) float ST[512];          // [ctx 0:128 | h1 128:384 | h2 384:512]
  __shared__ __align__(16) float b2loc[128];       // cell*4+gate
  __shared__ float att[128];
  __shared__ unsigned int sflag[4];                // LDS epoch flags: A,B,C

  if (tid < 512) ST[tid] = 0.f;
  if (tid == 0){ sflag[0]=0; sflag[1]=0; sflag[2]=0; }
  if (tid < 128){
    int c = tid >> 2, g = tid & 3;
    b2loc[tid] = bi2[g*128 + r*32 + c] + bh2[g*128 + r*32 + c];
  }
  // stage key slice: keyT[b][k][r*128 .. r*128+128)
  {
    const float4* kg = reinterpret_cast<const float4*>(keyT + (size_t)b*KEYDD*TT);
    float4* kl = reinterpret_cast<float4*>(key_lds);
    #pragma unroll
    for (int i = 0; i < 4; ++i){
      int q = tid + i*1024;            // 0..4095
      int k = q >> 5, c = q & 31;
      kl[k*32 + c] = kg[(size_t)k*128 + r*32 + c];
    }
  }
  // values slice to registers: thread (vg = tid&31, sc = tid>>5) holds s = sc*4+i
  const int vg = tid & 31, sc = tid >> 5;
  const float4* valB4 = reinterpret_cast<const float4*>(values + (size_t)b*TT*VALDD);
  float4 vv0 = valB4[(size_t)(r*128 + sc*4 + 0)*32 + vg];
  float4 vv1 = valB4[(size_t)(r*128 + sc*4 + 1)*32 + vg];
  float4 vv2 = valB4[(size_t)(r*128 + sc*4 + 2)*32 + vg];
  float4 vv3 = valB4[(size_t)(r*128 + sc*4 + 3)*32 + vg];

  float c1 = 0.f, c2 = 0.f;            // cell slices in regs (tid<64 / tid<32)
  __syncthreads();

  const float4* W1r4 = reinterpret_cast<const float4*>(W1T) + (size_t)r*384*64;
  const float4* W2r4 = reinterpret_cast<const float4*>(W2T) + (size_t)r*384*32;
  const float*  P1b  = P1 + (size_t)b*LL*1024;
  unsigned int* cA = cnt + (b*3 + 0)*64;
  unsigned int* cB = cnt + (b*3 + 1)*64;
  unsigned int* cC = cnt + (b*3 + 2)*64;
  float* axb = axc + (size_t)b*NB*132;
  float* h1g = h1buf + b*256;
  float* h2g = h2buf + b*128;

  const int ogA = tid & 63, kcA = tid >> 6;   // LSTM1: 64 cells(x4 gates) x 16 k-chunks
  const int ogB = tid & 31, kcB = tid >> 5;   // LSTM2: 32 cells(x4 gates) x 32 k-chunks
  float4* part4 = reinterpret_cast<float4*>(part);

  // ---- prologue: h1[0] from P1 only (h1prev=0, ctx=0)
  if (tid < 64){
    float s0 = P1b[      r*64 + tid];
    float s2 = P1b[512 + r*64 + tid];
    float s3 = P1b[768 + r*64 + tid];
    float c = sigm(s0)*ftanh(s2);            // f-gate * 0 dropped
    c1 = c;
    g_store(h1g + r*64 + tid, sigm(s3)*ftanh(c));
    wave_arrive(cA);
    spin_wait(cA, NB);
    if (tid == 0) *(volatile unsigned*)&sflag[0] = 1u;
  }
  lds_waitf(&sflag[0], 1u);
  {
    float h1v = (tid < 256) ? g_load(h1g + tid) : 0.f;
    if (tid < 256) ST[128+tid] = h1v;
  }
  bar();
  // B2(0): h1 rows only (h2prev = 0)
  {
    float4 accB = make_float4(0.f,0.f,0.f,0.f);
    const float4* wp = W2r4 + (size_t)(128 + kcB*8)*32 + ogB;
    #pragma unroll
    for (int i = 0; i < 8; ++i){
      float4 w = wp[(size_t)i*32];
      float  x = ST[128 + kcB*8 + i];
      accB.x += x*w.x; accB.y += x*w.y; accB.z += x*w.z; accB.w += x*w.w;
    }
    part4[kcB*32 + ogB] = accB;
  }
  bar();
  if (tid < 32){
    float4 s = reinterpret_cast<const float4*>(b2loc)[tid];
    #pragma unroll
    for (int kc = 0; kc < 32; ++kc){
      float4 p = part4[kc*32 + tid];
      s.x += p.x; s.y += p.y; s.z += p.z; s.w += p.w;
    }
    float c = sigm(s.y)*c2 + sigm(s.x)*ftanh(s.z); c2 = c;
    float h2 = sigm(s.w)*ftanh(c);
    g_store(h2g + r*32 + tid, h2);
    states[((size_t)b*LL + 0)*256 + r*32 + tid] = h2;
  }
  if (tid < 64) wave_arrive(cB);

  // ---- main loop: iter t computes C(t) and (if t<LL-1) h1[t+1], h2[t+1]
  for (int t = 0; t < LL; ++t){
    const bool last = (t == LL-1);
    float p10=0.f, p11=0.f, p12=0.f, p13=0.f;
    if (!last && tid < 64){
      const float* pp = P1b + (size_t)(t+1)*1024;
      p10 = pp[      r*64 + tid];
      p11 = pp[256 + r*64 + tid];
      p12 = pp[512 + r*64 + tid];
      p13 = pp[768 + r*64 + tid];
    }
    float4 accA = make_float4(0.f,0.f,0.f,0.f);
    if (!last){                                  // A1a: h1 rows, i 0..3
      const float4* wp = W1r4 + (size_t)(kcA*16)*64 + ogA;
      #pragma unroll
      for (int i = 0; i < 4; ++i){
        float4 w = wp[(size_t)i*64];
        float  x = ST[128 + kcA*16 + i];
        accA.x += x*w.x; accA.y += x*w.y; accA.z += x*w.z; accA.w += x*w.w;
      }
    }
    // wait h2[t]: wave0 spins globally, publishes to LDS flag
    if (tid < 64){
      spin_wait(cB, (unsigned)((t+1)*NB));
      if (tid == 0) *(volatile unsigned*)&sflag[1] = (unsigned)(t+1);
    }
    lds_waitf(&sflag[1], (unsigned)(t+1));
    float hv = (tid < 128) ? g_load(h2g + tid) : 0.f;
    if (!last){                                  // A1b: i 4..11 (covers fill latency)
      const float4* wp = W1r4 + (size_t)(kcA*16 + 4)*64 + ogA;
      #pragma unroll
      for (int i = 0; i < 8; ++i){
        float4 w = wp[(size_t)i*64];
        float  x = ST[128 + kcA*16 + 4 + i];
        accA.x += x*w.x; accA.y += x*w.y; accA.z += x*w.z; accA.w += x*w.w;
      }
    }
    if (tid < 128) ST[384+tid] = hv;
    bar();                                                          // (1)

    // ---- C(t): energies from LDS key x h2 — 128 s-threads x 8 k-chunks(16)
    {
      const int s = tid & 127, kc = tid >> 7;
      const float* kp = key_lds + (size_t)(kc*16)*128 + s;
      float acc = 0.f;
      #pragma unroll
      for (int i = 0; i < 16; ++i)
        acc += kp[(size_t)i*128] * ST[384 + kc*16 + i];
      part[kc*128 + s] = acc;
    }
    bar();                                                          // (2)
    // softmax by wave0 (lane handles s=lane, s=64+lane)
    float Mreg = 0.f, Sreg = 0.f;
    if (tid < 64){
      float ea = 0.f, eb = 0.f;
      #pragma unroll
      for (int kc = 0; kc < 8; ++kc){
        ea += part[kc*128 + tid];
        eb += part[kc*128 + 64 + tid];
      }
      float m = fmaxf(ea, eb);
      #pragma unroll
      for (int off = 32; off > 0; off >>= 1) m = fmaxf(m, __shfl_xor(m, off));
      float pa = __expf(ea - m), pb = __expf(eb - m);
      float ss = pa + pb;
      #pragma unroll
      for (int off = 32; off > 0; off >>= 1) ss += __shfl_xor(ss, off);
      att[tid] = pa; att[64+tid] = pb;
      Mreg = m; Sreg = ss;
    }
    bar();                                                          // (3)
    // ctx partial from register-resident values
    {
      float a0 = att[sc*4+0], a1 = att[sc*4+1], a2 = att[sc*4+2], a3 = att[sc*4+3];
      float4 acc;
      acc.x = a0*vv0.x + a1*vv1.x + a2*vv2.x + a3*vv3.x;
      acc.y = a0*vv0.y + a1*vv1.y + a2*vv2.y + a3*vv3.y;
      acc.z = a0*vv0.z + a1*vv1.z + a2*vv2.z + a3*vv3.z;
      acc.w = a0*vv0.w + a1*vv1.w + a2*vv2.w + a3*vv3.w;
      part4[sc*32 + vg] = acc;
    }
    bar();                                                          // (4)
    if (tid < 128){
      float cx = 0.f;
      #pragma unroll
      for (int kc = 0; kc < 32; ++kc) cx += part[kc*128 + tid];
      g_store(axb + r*132 + tid, cx);
      if (tid == 0){ g_store(axb + r*132 + 128, Mreg); g_store(axb + r*132 + 129, Sreg); }
    }
    if (tid < 128) wave_arrive(cC);              // waves 0,1 each post (+2/block)

    if (!last){                                  // A1c: i 12..15 (covers cC skew)
      const float4* wp = W1r4 + (size_t)(kcA*16 + 12)*64 + ogA;
      #pragma unroll
      for (int i = 0; i < 4; ++i){
        float4 w = wp[(size_t)i*64];
        float  x = ST[128 + kcA*16 + 12 + i];
        accA.x += x*w.x; accA.y += x*w.y; accA.z += x*w.z; accA.w += x*w.w;
      }
    }
    // wait ctx partials; flash combine
    if (tid < 64){
      spin_wait(cC, (unsigned)(2u*(t+1)*NB));
      if (tid == 0) *(volatile unsigned*)&sflag[2] = (unsigned)(t+1);
    }
    lds_waitf(&sflag[2], (unsigned)(t+1));
    if (tid < 128){
      float m0 = g_load(axb+128),     m1 = g_load(axb+132+128);
      float m2 = g_load(axb+264+128), m3 = g_load(axb+396+128);
      float s0 = g_load(axb+129),     s1 = g_load(axb+132+129);
      float s2 = g_load(axb+264+129), s3 = g_load(axb+396+129);
      float x0 = g_load(axb+tid),     x1 = g_load(axb+132+tid);
      float x2 = g_load(axb+264+tid), x3 = g_load(axb+396+tid);
      float M  = fmaxf(fmaxf(m0,m1), fmaxf(m2,m3));
      float w0 = __expf(m0-M), w1 = __expf(m1-M), w2 = __expf(m2-M), w3 = __expf(m3-M);
      float inv = 1.0f/(w0*s0 + w1*s1 + w2*s2 + w3*s3);
      float cx  = (w0*x0 + w1*x1 + w2*x2 + w3*x3)*inv;
      ST[tid] = cx;
      if ((tid >> 5) == r)
        states[((size_t)b*LL + t)*256 + 128 + tid] = cx;
    }
    bar();                                                          // (5)
    if (last) break;

    // ---- A2: ctx rows; complete LSTM1 gates for t+1
    {
      const float4* wp = W1r4 + (size_t)(256 + kcA*8)*64 + ogA;
      #pragma unroll
      for (int i = 0; i < 8; ++i){
        float4 w = wp[(size_t)i*64];
        float  x = ST[kcA*8 + i];
        accA.x += x*w.x; accA.y += x*w.y; accA.z += x*w.z; accA.w += x*w.w;
      }
      part4[kcA*64 + ogA] = accA;
    }
    bar();                                                          // (6)
    if (tid < 64){
      float4 s = make_float4(p10, p11, p12, p13);
      #pragma unroll
      for (int kc = 0; kc < 16; ++kc){
        float4 p = part4[kc*64 + tid];
        s.x += p.x; s.y += p.y; s.z += p.z; s.w += p.w;
      }
      float c = sigm(s.y)*c1 + sigm(s.x)*ftanh(s.z); c1 = c;
      g_store(h1g + r*64 + tid, sigm(s.w)*ftanh(c));
      wave_arrive(cA);
    }
    // ---- B1: h2prev rows (covers cA flight) — uses ST[384:512] = h2[t]
    float4 accB = make_float4(0.f,0.f,0.f,0.f);
    {
      const float4* wp = W2r4 + (size_t)(kcB*4)*32 + ogB;
      #pragma unroll
      for (int i = 0; i < 4; ++i){
        float4 w = wp[(size_t)i*32];
        float  x = ST[384 + kcB*4 + i];
        accB.x += x*w.x; accB.y += x*w.y; accB.z += x*w.z; accB.w += x*w.w;
      }
    }
    if (tid < 64){
      spin_wait(cA, (unsigned)((t+2)*NB));
      if (tid == 0) *(volatile unsigned*)&sflag[0] = (unsigned)(t+2);
    }
    lds_waitf(&sflag[0], (unsigned)(t+2));
    {
      float h1v = (tid < 256) ? g_load(h1g + tid) : 0.f;
      if (tid < 256) ST[128+tid] = h1v;
    }
    bar();                                                          // (7)
    // ---- B2: h1 rows
    {
      const float4* wp = W2r4 + (size_t)(128 + kcB*8)*32 + ogB;
      #pragma unroll
      for (int i = 0; i < 8; ++i){
        float4 w = wp[(size_t)i*32];
        float  x = ST[128 + kcB*8 + i];
        accB.x += x*w.x; accB.y += x*w.y; accB.z += x*w.z; accB.w += x*w.w;
      }
      part4[kcB*32 + ogB] = accB;
    }
    bar();                                                          // (8)
    if (tid < 32){
      float4 s = reinterpret_cast<const float4*>(b2loc)[tid];
      #pragma unroll
      for (int kc = 0; kc < 32; ++kc){
        float4 p = part4[kc*32 + tid];
        s.x += p.x; s.y += p.y; s.z += p.z; s.w += p.w;
      }
      float c = sigm(s.y)*c2 + sigm(s.x)*ftanh(s.z); c2 = c;
      float h2 = sigm(s.w)*ftanh(c);
      g_store(h2g + r*32 + tid, h2);
      states[((size_t)b*LL + t + 1)*256 + r*32 + tid] = h2;
    }
    if (tid < 64) wave_arrive(cB);
  }
}

// ---------------------------------------------------------------------------
// Final logits GEMM: C[n][v] = states[n][:] . emb[v][:] + b_out[v]
__global__ __launch_bounds__(256) void gemm_kernel(
    const float* __restrict__ A, const float* __restrict__ Bm,
    const float* __restrict__ bias, float* __restrict__ C)
{
  __shared__ float As[16][132];
  __shared__ float Bs[16][132];
  const int tid = threadIdx.x;
  const int tx = tid & 15, ty = tid >> 4;
  const int bn = blockIdx.x, bm = blockIdx.y;

  float acc[8][8];
  #pragma unroll
  for (int i = 0; i < 8; ++i)
    #pragma unroll
    for (int j = 0; j < 8; ++j) acc[i][j] = 0.f;

  const int r  = tid >> 1;
  const int ko = (tid & 1) * 8;
  const float* Ap = A  + ((size_t)(bm*128 + r))*256 + ko;
  const float* Bp = Bm + ((size_t)(bn*128 + r))*256 + ko;

  for (int k0 = 0; k0 < 256; k0 += 16){
    float4 a0 = *(const float4*)(Ap + k0);
    float4 a1 = *(const float4*)(Ap + k0 + 4);
    float4 b0 = *(const float4*)(Bp + k0);
    float4 b1 = *(const float4*)(Bp + k0 + 4);
    As[ko+0][r]=a0.x; As[ko+1][r]=a0.y; As[ko+2][r]=a0.z; As[ko+3][r]=a0.w;
    As[ko+4][r]=a1.x; As[ko+5][r]=a1.y; As[ko+6][r]=a1.z; As[ko+7][r]=a1.w;
    Bs[ko+0][r]=b0.x; Bs[ko+1][r]=b0.y; Bs[ko+2][r]=b0.z; Bs[ko+3][r]=b0.w;
    Bs[ko+4][r]=b1.x; Bs[ko+5][r]=b1.y; Bs[ko+6][r]=b1.z; Bs[ko+7][r]=b1.w;
    __syncthreads();
    #pragma unroll
    for (int k = 0; k < 16; ++k){
      float4 x0 = *(const float4*)&As[k][ty*8];
      float4 x1 = *(const float4*)&As[k][ty*8+4];
      float4 y0 = *(const float4*)&Bs[k][tx*8];
      float4 y1 = *(const float4*)&Bs[k][tx*8+4];
      float av[8] = {x0.x,x0.y,x0.z,x0.w,x1.x,x1.y,x1.z,x1.w};
      float bv[8] = {y0.x,y0.y,y0.z,y0.w,y1.x,y1.y,y1.z,y1.w};
      #pragma unroll
      for (int i = 0; i < 8; ++i)
        #pragma unroll
        for (int j = 0; j < 8; ++j) acc[i][j] += av[i]*bv[j];
    }
    __syncthreads();
  }

  const int c0 = bn*128 + tx*8;
  float bl[8];
  #pragma unroll
  for (int j = 0; j < 8; ++j) bl[j] = bias[c0 + j];
  #pragma unroll
  for (int i = 0; i < 8; ++i){
    size_t row = (size_t)(bm*128 + ty*8 + i);
    float4 o0 = make_float4(acc[i][0]+bl[0], acc[i][1]+bl[1], acc[i][2]+bl[2], acc[i][3]+bl[3]);
    float4 o1 = make_float4(acc[i][4]+bl[4], acc[i][5]+bl[5], acc[i][6]+bl[6], acc[i][7]+bl[7]);
    *(float4*)(C + row*4096 + c0)     = o0;
    *(float4*)(C + row*4096 + c0 + 4) = o1;
  }
}

extern "C" void kernel_launch(void* const* d_in, const int* in_sizes, int n_in,
                              void* d_out, int out_size, void* d_ws, size_t ws_size,
                              hipStream_t stream)
{
  const float* key    = (const float*)d_in[0];
  const float* values = (const float*)d_in[1];
  // d_in[2] = lens (unused by reference path)
  const int*   text   = (const int*)  d_in[3];
  const float* emb    = (const float*)d_in[4];
  const float* Wi1    = (const float*)d_in[5];
  const float* Wh1    = (const float*)d_in[6];
  const float* bi1    = (const float*)d_in[7];
  const float* bh1    = (const float*)d_in[8];
  const float* Wi2    = (const float*)d_in[9];
  const float* Wh2    = (const float*)d_in[10];
  const float* bi2    = (const float*)d_in[11];
  const float* bh2    = (const float*)d_in[12];
  const float* bout   = (const float*)d_in[13];

  // workspace (floats): states[16384*256] | W1T[4*384*256] | W2T[4*384*128] (~19.1 MB)
  float* states = (float*)d_ws;
  float* W1T    = states + (size_t)BB*LL*256;
  float* W2T    = W1T + (size_t)NB*384*256;

  // scratch inside d_out (268 MB; dead until final GEMM overwrites it):
  // P1[16384*1024] | keyT[64*128*512] | h1buf[64*256] | h2buf[64*128]
  // | axc[64*4*132] | cnt[64*3*64 uint]
  float* P1    = (float*)d_out;
  float* keyT  = P1 + (size_t)16384*1024;
  float* h1buf = keyT + (size_t)BB*KEYDD*TT;
  float* h2buf = h1buf + (size_t)BB*256;
  float* axc   = h2buf + (size_t)BB*128;
  unsigned int* cnt = (unsigned int*)(axc + (size_t)BB*NB*132);

  prep_w   <<<1536, 256, 0, stream>>>(Wi1, Wh1, Wi2, Wh2, W1T, W2T, cnt);
  prep_keyT<<<4096, 256, 0, stream>>>(key, keyT);
  pre_gemm <<<dim3(1024/128, 16384/128), 256, 0, stream>>>(text, emb, Wi1, bi1, bh1, P1);
  rec_kernel<<<BB*NB, 1024, 0, stream>>>(keyT, values, P1, W1T, W2T, bi2, bh2, states,
                                         h1buf, h2buf, axc, cnt);
  dim3 grid(VOC/128, (BB*LL)/128);
  gemm_kernel<<<grid, 256, 0, stream>>>(states, emb, bout, (float*)d_out);
}